// Round 4
// baseline (88.913 us; speedup 1.0000x reference)
//
#include <hip/hip_runtime.h>

// ReflectionRayTracer: 8192 rays x 2048 quad surfaces. out[ray][surf] = t*mask.
//
// R4: 4 consecutive surfaces per thread.
//  - one global_store_dwordx4 per ray per thread (1 KiB/wave-instr) instead of
//    4 scalar dword stores -> 4x fewer store instructions + addressing.
//  - 6 uniform ray loads amortized over 4 pairs.
//  - per-pair math unchanged from R3 (bitwise-identical: 3-fma dots, rcp-mul t,
//    min3 + cndmask mask) => absmax should stay exactly 4.03125.
// Precompute kernel (per-surface plane + affine r-dot coefficient vectors with
// all _safe() divides folded) unchanged, writes 16 f32/surface to d_ws.
//
// Roofline: VALU ~5 us + rcp ~3 us issue, store floor 64 MiB / ~6 TB/s ~ 11 us.
// Target trace ~13-15 us.

#define N_RAYS 8192
#define N_SURF 2048
constexpr int SPT = 4;    // surfaces per thread (float4 store)
constexpr int RPB = 16;   // rays per block; grid = (2, 512) = 1024 blocks

__device__ __forceinline__ float safef(float x) {
    return (x == 0.0f) ? 1e-18f : x;   // jnp.where(x==0, EPS, x)
}

__device__ __forceinline__ void surface_coeffs(
    const float* __restrict__ V, int s,
    float4& c0, float4& c1, float4& c2, float4& c3)
{
    const float4 p0 = *(const float4*)(V + (size_t)s * 12);
    const float4 p1 = *(const float4*)(V + (size_t)s * 12 + 4);
    const float4 p2 = *(const float4*)(V + (size_t)s * 12 + 8);
    const float ax = p0.x, ay = p0.y, az = p0.z;       // a = V[s][0]
    const float bx = p0.w, by = p1.x, bz = p1.y;       // b = V[s][1]
    const float cx = p1.z, cy = p1.w, cz = p2.x;       // c = V[s][2]
    const float wx = p2.y, wy = p2.z, wz = p2.w;       // V[s][3]

    // Plane: v = normalize(cross(b-a, c-a)); k = -dot(v, V[s][3])
    const float e0x = bx - ax, e0y = by - ay, e0z = bz - az;
    const float e1x = cx - ax, e1y = cy - ay, e1z = cz - az;
    const float nx = e0y * e1z - e0z * e1y;
    const float ny = e0z * e1x - e0x * e1z;
    const float nz = e0x * e1y - e0y * e1x;
    const float nrm = sqrtf(nx * nx + ny * ny + nz * nz);
    const float vx = nx / nrm, vy = ny / nrm, vz = nz / nrm;
    const float k = -(vx * wx + vy * wy + vz * wz);

    // Reference constants:
    const float B  = ax * bz - az * bx;
    const float D  = ax * by - ay * bx;                 // G == D
    const float E  = ax * cz - az * cx;
    const float P  = ay * cx - ax * cy;
    const float F  = B * P;
    const float den_g = safef(D * (E * D + F));         // _safe(D*(E*G+F))
    const float sD    = safef(D);
    const float sAX   = safef(ax);

    // gam = g . r
    const float DB = D * B, DD = D * D;
    const float g0 = (DB * ay - DD * az) / den_g;
    const float g1 = -(DB * ax) / den_g;
    const float g2 = (DD * ax) / den_g;
    // beta = (-ay*rx + ax*ry + P*gam)/sD  ->  bb . r
    const float b0 = -ay / sD, b1 = ax / sD, bp = P / sD;
    const float bb0 = b0 + bp * g0;
    const float bb1 = b1 + bp * g1;
    const float bb2 = bp * g2;
    // alpha = (rx - bx*beta - cx*gam)/sAX  ->  aa . r
    const float a0 = 1.0f / sAX, ab = -bx / sAX, ac = -cx / sAX;
    const float aa0 = a0 + ab * bb0 + ac * g0;
    const float aa1 = ab * bb1 + ac * g1;
    const float aa2 = ab * bb2 + ac * g2;

    c0 = make_float4(vx, vy, vz, k);
    c1 = make_float4(g0, g1, g2, 0.0f);
    c2 = make_float4(bb0, bb1, bb2, 0.0f);
    c3 = make_float4(aa0, aa1, aa2, 0.0f);
}

__global__ __launch_bounds__(256) void precompute_kernel(
    const float* __restrict__ V, float* __restrict__ C)
{
    const int s = blockIdx.x * 256 + threadIdx.x;
    float4 c0, c1, c2, c3;
    surface_coeffs(V, s, c0, c1, c2, c3);
    float4* c4 = (float4*)(C + (size_t)s * 16);
    c4[0] = c0; c4[1] = c1; c4[2] = c2; c4[3] = c3;
}

__global__ __launch_bounds__(256) void trace_kernel(
    const float* __restrict__ o, const float* __restrict__ dr,
    const float* __restrict__ C, float* __restrict__ out)
{
    const int s0 = (blockIdx.x * 256 + threadIdx.x) * SPT;   // 4 consecutive surfaces

    float4 c0[SPT], c1[SPT], c2[SPT], c3[SPT];
#pragma unroll
    for (int j = 0; j < SPT; ++j) {
        const float4* c4 = (const float4*)(C + (size_t)(s0 + j) * 16);
        c0[j] = c4[0]; c1[j] = c4[1]; c2[j] = c4[2]; c3[j] = c4[3];
    }

    const int ray0 = blockIdx.y * RPB;
    float* outp = out + (size_t)ray0 * N_SURF + s0;
#pragma unroll 2
    for (int i = 0; i < RPB; ++i) {
        const int ray = ray0 + i;
        // Block-uniform ray loads -> scalar loads, amortized over SPT pairs.
        const float o0 = o[ray * 3 + 0], o1 = o[ray * 3 + 1], o2 = o[ray * 3 + 2];
        const float d0 = dr[ray * 3 + 0], d1 = dr[ray * 3 + 1], d2 = dr[ray * 3 + 2];

        float res[SPT];
#pragma unroll
        for (int j = 0; j < SPT; ++j) {
            const float vo_k = fmaf(o0, c0[j].x, fmaf(o1, c0[j].y, fmaf(o2, c0[j].z, c0[j].w)));
            const float vd   = fmaf(d0, c0[j].x, fmaf(d1, c0[j].y, d2 * c0[j].z));
            const float t    = -vo_k * __builtin_amdgcn_rcpf(vd);

            const float rx = fmaf(t, d0, o0);
            const float ry = fmaf(t, d1, o1);
            const float rz = fmaf(t, d2, o2);

            const float gam   = fmaf(c1[j].x, rx, fmaf(c1[j].y, ry, c1[j].z * rz));
            const float beta  = fmaf(c2[j].x, rx, fmaf(c2[j].y, ry, c2[j].z * rz));
            const float alpha = fmaf(c3[j].x, rx, fmaf(c3[j].y, ry, c3[j].z * rz));

            const float mn = fminf(fminf(beta, gam), alpha);   // v_min3_f32
            res[j] = (mn > 0.0f) ? t : 0.0f;
        }
        *(float4*)(outp + (size_t)i * N_SURF) = *(const float4*)res;  // 16B aligned: s0 % 4 == 0
    }
}

extern "C" void kernel_launch(void* const* d_in, const int* in_sizes, int n_in,
                              void* d_out, int out_size, void* d_ws, size_t ws_size,
                              hipStream_t stream) {
    const float* o  = (const float*)d_in[0];
    const float* dr = (const float*)d_in[1];
    const float* V  = (const float*)d_in[2];
    float* out = (float*)d_out;
    float* C = (float*)d_ws;   // 2048 * 16 * 4 B = 128 KiB

    precompute_kernel<<<dim3(N_SURF / 256), dim3(256), 0, stream>>>(V, C);
    trace_kernel<<<dim3(N_SURF / (256 * SPT), N_RAYS / RPB), dim3(256), 0, stream>>>(o, dr, C, out);
}

// Round 5
// 85.880 us; speedup vs baseline: 1.0353x; 1.0353x over previous
//
#include <hip/hip_runtime.h>

// ReflectionRayTracer: 8192 rays x 2048 quad surfaces. out[ray][surf] = t*mask.
//
// R5: single fused kernel, occupancy-first (R3/R4 A/B showed the trace loop is
// latency-bound, not store-issue-bound: full-occupancy scalar stores beat
// quarter-occupancy float4 stores).
//  - SPT=1: each thread owns one surface and computes its own coefficients
//    inline (no precompute kernel -> no second launch, no inter-kernel gap).
//  - Preamble uses v_rsq/v_rcp instead of 13 IEEE divides (~80 VALU, amortized
//    over RPB=32 rays ~ 2.5 instr/pair). Perturbation ~1e-7 relative — same
//    class as R3's rcp-for-t which added zero mask flips (absmax frozen at
//    4.03125 across R2-R4, threshold 7.24).
//  - __launch_bounds__(256, 8): cap at 64 VGPR -> 8 waves/SIMD, 32 waves/CU
//    (live set ~40 regs). Grid (8,256) = 2048 blocks = 8 blocks/CU.
//  - Nontemporal dword stores: 64 MiB written once, never read -> skip L2
//    dirty-eviction path (output is 2x aggregate L2).
// Per-pair loop: 2 fma-dots + rcp-mul t + 3 fma (r) + 3 fma-dots + min3 + sel
// ~ 23 VALU + 1 rcp.

#define N_RAYS 8192
#define N_SURF 2048
constexpr int RPB = 32;   // rays per block; grid = (2048/256, 8192/32) = (8,256)

__device__ __forceinline__ float safef(float x) {
    return (x == 0.0f) ? 1e-18f : x;   // jnp.where(x==0, EPS, x)
}

__global__ __launch_bounds__(256, 8) void trace_kernel(
    const float* __restrict__ o, const float* __restrict__ dr,
    const float* __restrict__ V, float* __restrict__ out)
{
    const int s = blockIdx.x * 256 + threadIdx.x;   // one surface per thread

    // ---- per-surface preamble (amortized over RPB rays) ----
    const float4 p0 = *(const float4*)(V + (size_t)s * 12);
    const float4 p1 = *(const float4*)(V + (size_t)s * 12 + 4);
    const float4 p2 = *(const float4*)(V + (size_t)s * 12 + 8);
    const float ax = p0.x, ay = p0.y, az = p0.z;       // a = V[s][0]
    const float bx = p0.w, by = p1.x, bz = p1.y;       // b = V[s][1]
    const float cx = p1.z, cy = p1.w, cz = p2.x;       // c = V[s][2]
    const float wx = p2.y, wy = p2.z, wz = p2.w;       // V[s][3]

    // Plane: v = normalize(cross(b-a, c-a)); k = -dot(v, V[s][3])
    const float e0x = bx - ax, e0y = by - ay, e0z = bz - az;
    const float e1x = cx - ax, e1y = cy - ay, e1z = cz - az;
    const float nx = e0y * e1z - e0z * e1y;
    const float ny = e0z * e1x - e0x * e1z;
    const float nz = e0x * e1y - e0y * e1x;
    const float rn = __builtin_amdgcn_rsqf(fmaf(nx, nx, fmaf(ny, ny, nz * nz)));
    const float vx = nx * rn, vy = ny * rn, vz = nz * rn;
    const float k = -fmaf(vx, wx, fmaf(vy, wy, vz * wz));

    // Reference constants:
    const float B  = ax * bz - az * bx;
    const float D  = ax * by - ay * bx;                 // G == D
    const float E  = ax * cz - az * cx;
    const float P  = ay * cx - ax * cy;
    const float F  = B * P;
    const float rden = __builtin_amdgcn_rcpf(safef(D * fmaf(E, D, F)));  // 1/_safe(D*(E*G+F))
    const float rD   = __builtin_amdgcn_rcpf(safef(D));
    const float rAX  = __builtin_amdgcn_rcpf(safef(ax));

    // gam = g . r
    const float DB = D * B, DD = D * D;
    const float g0 = (DB * ay - DD * az) * rden;
    const float g1 = -(DB * ax) * rden;
    const float g2 = (DD * ax) * rden;
    // beta = (-ay*rx + ax*ry + P*gam)/D  ->  bb . r
    const float bp  = P * rD;
    const float bb0 = fmaf(bp, g0, -ay * rD);
    const float bb1 = fmaf(bp, g1,  ax * rD);
    const float bb2 = bp * g2;
    // alpha = (rx - bx*beta - cx*gam)/ax  ->  aa . r
    const float ab = -bx * rAX, ac = -cx * rAX;
    const float aa0 = fmaf(ab, bb0, fmaf(ac, g0, rAX));
    const float aa1 = fmaf(ab, bb1, ac * g1);
    const float aa2 = fmaf(ab, bb2, ac * g2);

    // ---- ray loop ----
    const int ray0 = blockIdx.y * RPB;
    float* outp = out + (size_t)ray0 * N_SURF + s;
#pragma unroll 4
    for (int i = 0; i < RPB; ++i) {
        const int ray = ray0 + i;
        // Wave-uniform ray loads -> scalar (SMEM) loads, scalar-cache hot.
        const float o0 = o[ray * 3 + 0], o1 = o[ray * 3 + 1], o2 = o[ray * 3 + 2];
        const float d0 = dr[ray * 3 + 0], d1 = dr[ray * 3 + 1], d2 = dr[ray * 3 + 2];

        const float vo_k = fmaf(o0, vx, fmaf(o1, vy, fmaf(o2, vz, k)));   // k + v.o
        const float vd   = fmaf(d0, vx, fmaf(d1, vy, d2 * vz));
        const float t    = -vo_k * __builtin_amdgcn_rcpf(vd);

        const float rx = fmaf(t, d0, o0);
        const float ry = fmaf(t, d1, o1);
        const float rz = fmaf(t, d2, o2);

        const float gam   = fmaf(g0,  rx, fmaf(g1,  ry, g2  * rz));
        const float beta  = fmaf(bb0, rx, fmaf(bb1, ry, bb2 * rz));
        const float alpha = fmaf(aa0, rx, fmaf(aa1, ry, aa2 * rz));

        const float mn  = fminf(fminf(beta, gam), alpha);   // v_min3_f32
        const float val = (mn > 0.0f) ? t : 0.0f;
        __builtin_nontemporal_store(val, outp + (size_t)i * N_SURF);
    }
}

extern "C" void kernel_launch(void* const* d_in, const int* in_sizes, int n_in,
                              void* d_out, int out_size, void* d_ws, size_t ws_size,
                              hipStream_t stream) {
    const float* o  = (const float*)d_in[0];
    const float* dr = (const float*)d_in[1];
    const float* V  = (const float*)d_in[2];
    float* out = (float*)d_out;

    trace_kernel<<<dim3(N_SURF / 256, N_RAYS / RPB), dim3(256), 0, stream>>>(o, dr, V, out);
}

// Round 6
// 84.915 us; speedup vs baseline: 1.0471x; 1.0114x over previous
//
#include <hip/hip_runtime.h>

// ReflectionRayTracer: 8192 rays x 2048 quad surfaces. out[ray][surf] = t*mask.
//
// R6: R5 with ONE change — plain stores instead of nontemporal. The 64 MiB
// output fits in the 256 MiB Infinity Cache; writeback stores let L2/L3 absorb
// the stream at cache speed with lazy HBM drain, while R5's NT flag forced
// every line down the synchronous HBM write path (~2.8 TB/s effective for this
// scattered-256B-chunk pattern vs ~6 TB/s for the harness's linear fill).
// Structure (from R5, kept):
//  - single fused kernel, one surface per thread, coeff preamble inline with
//    rsq/rcp (amortized over RPB=32 rays).
//  - per-pair loop: 2 fma-dots + rcp-mul t + 3 fma (r) + 3 fma-dots +
//    min3 + cndmask ~ 25 VALU + 1 trans.
//  - __launch_bounds__(256,8): <=64 VGPR, 8 waves/SIMD, grid (8,256) = 8 blocks/CU.
// Values are bit-identical to R5 => absmax should be exactly 2.578125.

#define N_RAYS 8192
#define N_SURF 2048
constexpr int RPB = 32;   // rays per block; grid = (2048/256, 8192/32) = (8,256)

__device__ __forceinline__ float safef(float x) {
    return (x == 0.0f) ? 1e-18f : x;   // jnp.where(x==0, EPS, x)
}

__global__ __launch_bounds__(256, 8) void trace_kernel(
    const float* __restrict__ o, const float* __restrict__ dr,
    const float* __restrict__ V, float* __restrict__ out)
{
    const int s = blockIdx.x * 256 + threadIdx.x;   // one surface per thread

    // ---- per-surface preamble (amortized over RPB rays) ----
    const float4 p0 = *(const float4*)(V + (size_t)s * 12);
    const float4 p1 = *(const float4*)(V + (size_t)s * 12 + 4);
    const float4 p2 = *(const float4*)(V + (size_t)s * 12 + 8);
    const float ax = p0.x, ay = p0.y, az = p0.z;       // a = V[s][0]
    const float bx = p0.w, by = p1.x, bz = p1.y;       // b = V[s][1]
    const float cx = p1.z, cy = p1.w, cz = p2.x;       // c = V[s][2]
    const float wx = p2.y, wy = p2.z, wz = p2.w;       // V[s][3]

    // Plane: v = normalize(cross(b-a, c-a)); k = -dot(v, V[s][3])
    const float e0x = bx - ax, e0y = by - ay, e0z = bz - az;
    const float e1x = cx - ax, e1y = cy - ay, e1z = cz - az;
    const float nx = e0y * e1z - e0z * e1y;
    const float ny = e0z * e1x - e0x * e1z;
    const float nz = e0x * e1y - e0y * e1x;
    const float rn = __builtin_amdgcn_rsqf(fmaf(nx, nx, fmaf(ny, ny, nz * nz)));
    const float vx = nx * rn, vy = ny * rn, vz = nz * rn;
    const float k = -fmaf(vx, wx, fmaf(vy, wy, vz * wz));

    // Reference constants:
    const float B  = ax * bz - az * bx;
    const float D  = ax * by - ay * bx;                 // G == D
    const float E  = ax * cz - az * cx;
    const float P  = ay * cx - ax * cy;
    const float F  = B * P;
    const float rden = __builtin_amdgcn_rcpf(safef(D * fmaf(E, D, F)));  // 1/_safe(D*(E*G+F))
    const float rD   = __builtin_amdgcn_rcpf(safef(D));
    const float rAX  = __builtin_amdgcn_rcpf(safef(ax));

    // gam = g . r
    const float DB = D * B, DD = D * D;
    const float g0 = (DB * ay - DD * az) * rden;
    const float g1 = -(DB * ax) * rden;
    const float g2 = (DD * ax) * rden;
    // beta = (-ay*rx + ax*ry + P*gam)/D  ->  bb . r
    const float bp  = P * rD;
    const float bb0 = fmaf(bp, g0, -ay * rD);
    const float bb1 = fmaf(bp, g1,  ax * rD);
    const float bb2 = bp * g2;
    // alpha = (rx - bx*beta - cx*gam)/ax  ->  aa . r
    const float ab = -bx * rAX, ac = -cx * rAX;
    const float aa0 = fmaf(ab, bb0, fmaf(ac, g0, rAX));
    const float aa1 = fmaf(ab, bb1, ac * g1);
    const float aa2 = fmaf(ab, bb2, ac * g2);

    // ---- ray loop ----
    const int ray0 = blockIdx.y * RPB;
    float* outp = out + (size_t)ray0 * N_SURF + s;
#pragma unroll 4
    for (int i = 0; i < RPB; ++i) {
        const int ray = ray0 + i;
        // Wave-uniform ray loads -> scalar (SMEM) loads.
        const float o0 = o[ray * 3 + 0], o1 = o[ray * 3 + 1], o2 = o[ray * 3 + 2];
        const float d0 = dr[ray * 3 + 0], d1 = dr[ray * 3 + 1], d2 = dr[ray * 3 + 2];

        const float vo_k = fmaf(o0, vx, fmaf(o1, vy, fmaf(o2, vz, k)));   // k + v.o
        const float vd   = fmaf(d0, vx, fmaf(d1, vy, d2 * vz));
        const float t    = -vo_k * __builtin_amdgcn_rcpf(vd);

        const float rx = fmaf(t, d0, o0);
        const float ry = fmaf(t, d1, o1);
        const float rz = fmaf(t, d2, o2);

        const float gam   = fmaf(g0,  rx, fmaf(g1,  ry, g2  * rz));
        const float beta  = fmaf(bb0, rx, fmaf(bb1, ry, bb2 * rz));
        const float alpha = fmaf(aa0, rx, fmaf(aa1, ry, aa2 * rz));

        const float mn = fminf(fminf(beta, gam), alpha);   // v_min3_f32
        outp[(size_t)i * N_SURF] = (mn > 0.0f) ? t : 0.0f; // plain store: L2/L3 writeback
    }
}

extern "C" void kernel_launch(void* const* d_in, const int* in_sizes, int n_in,
                              void* d_out, int out_size, void* d_ws, size_t ws_size,
                              hipStream_t stream) {
    const float* o  = (const float*)d_in[0];
    const float* dr = (const float*)d_in[1];
    const float* V  = (const float*)d_in[2];
    float* out = (float*)d_out;

    trace_kernel<<<dim3(N_SURF / 256, N_RAYS / RPB), dim3(256), 0, stream>>>(o, dr, V, out);
}